// Round 5
// baseline (1168.386 us; speedup 1.0000x reference)
//
#include <hip/hip_runtime.h>
#include <hip/hip_bf16.h>

// ---------------------------------------------------------------------------
// GCN via device-built CSR (no f32 atomics):
//   deg -> exclusive scan -> bucket fill sorted_row[]
//   3x [ hw = dinv * (hprev @ W) ;
//        hcat_k[n] = relu(dinv[n]*(hw[n] + sum_in hw[r]) + b) ]  (post-relu)
//   out = hcat @ Wlin + blin
// GEMMs: K=32 LDS chunks, reg-prefetch pipeline, spill-free launch bounds
// (VGPR budget: acc + prefetch + ~25 addressing must fit 512/waves_per_EU).
// ---------------------------------------------------------------------------

// ---- degree count: deg[col]++ ---------------------------------------------
__global__ __launch_bounds__(256) void k_deg(const int* __restrict__ col, int E,
                                             int* __restrict__ degi) {
  int e = blockIdx.x * 256 + threadIdx.x;
  if (e < E) atomicAdd(&degi[col[e]], 1);
}

// ---- dinv = rsqrt(1 + deg) ------------------------------------------------
__global__ __launch_bounds__(256) void k_dinv(const int* __restrict__ degi,
                                              float* __restrict__ dinv, int N) {
  int n = blockIdx.x * 256 + threadIdx.x;
  if (n < N) dinv[n] = rsqrtf(1.0f + (float)degi[n]);
}

// ---- scan pass 1: per-1024-chunk exclusive scan + block sums --------------
__global__ __launch_bounds__(256) void k_scan1(const int* __restrict__ degi, int N,
                                               int* __restrict__ offs,
                                               int* __restrict__ bsums) {
  __shared__ int sm[256];
  const int b = blockIdx.x, t = threadIdx.x;
  const int base = b * 1024 + t * 4;
  int v[4];
  #pragma unroll
  for (int i = 0; i < 4; ++i) v[i] = (base + i < N) ? degi[base + i] : 0;
  const int s = v[0] + v[1] + v[2] + v[3];
  sm[t] = s;
  __syncthreads();
  for (int ofs = 1; ofs < 256; ofs <<= 1) {
    const int add = (t >= ofs) ? sm[t - ofs] : 0;
    __syncthreads();
    sm[t] += add;
    __syncthreads();
  }
  if (t == 255) bsums[b] = sm[255];
  int run = sm[t] - s;
  #pragma unroll
  for (int i = 0; i < 4; ++i) {
    if (base + i < N) offs[base + i] = run;
    run += v[i];
  }
}

// ---- scan pass 2: exclusive scan of block sums (nb <= 128) ----------------
__global__ __launch_bounds__(128) void k_scan2(int* __restrict__ bsums, int nb) {
  __shared__ int sm[128];
  const int t = threadIdx.x;
  const int v = (t < nb) ? bsums[t] : 0;
  sm[t] = v;
  __syncthreads();
  for (int ofs = 1; ofs < 128; ofs <<= 1) {
    const int add = (t >= ofs) ? sm[t - ofs] : 0;
    __syncthreads();
    sm[t] += add;
    __syncthreads();
  }
  if (t < nb) bsums[t] = sm[t] - v;
}

// ---- scan pass 3: add block offset; copy to cursor ------------------------
__global__ __launch_bounds__(256) void k_scan3(int* __restrict__ offs,
                                               const int* __restrict__ bsums,
                                               int* __restrict__ cursor, int N) {
  const int add = bsums[blockIdx.x];
  const int base = blockIdx.x * 1024 + threadIdx.x * 4;
  #pragma unroll
  for (int i = 0; i < 4; ++i) {
    const int idx = base + i;
    if (idx < N) {
      const int o = offs[idx] + add;
      offs[idx] = o;
      cursor[idx] = o;
    }
  }
}

// ---- bucket fill: sorted_row[pos] = row ------------------------------------
__global__ __launch_bounds__(256) void k_fill(const int* __restrict__ rowi,
                                              const int* __restrict__ coli, int E,
                                              int* __restrict__ cursor,
                                              int* __restrict__ sorted_row) {
  int e = blockIdx.x * 256 + threadIdx.x;
  if (e < E) {
    const int pos = atomicAdd(&cursor[coli[e]], 1);
    sorted_row[pos] = rowi[e];
  }
}

// ---- layer GEMM: hw = dinv * (A @ W), K=128, 4 chunks of 32 ---------------
// (256,3): VGPR cap 170, need ~130 (acc 64 + pa/pw 32 + addressing). No spill.
__global__ __launch_bounds__(256, 3) void k_gemm128(
    const float* __restrict__ A, long long lda,
    const float* __restrict__ W, const float* __restrict__ dinv,
    float* __restrict__ hw, int N) {
  __shared__ __align__(16) float hsT[32][128];  // [k][r ^ k4]
  __shared__ __align__(16) float Ws[32][128];   // [k][c]
  const int tid = threadIdx.x;
  const int n0 = blockIdx.x * 128;
  const int rows = min(128, N - n0);
  const int tc = (tid & 15) << 3;
  const int tr = (tid >> 4) << 3;
  float acc[8][8] = {};
  float4 pa[4], pw[4];

  auto loadA = [&](int kc) {
    #pragma unroll
    for (int u = 0; u < 4; ++u) {
      const int i = tid + 256 * u;
      const int r = i >> 3, k4 = (i & 7) << 2;
      float4 v = make_float4(0.f, 0.f, 0.f, 0.f);
      if (r < rows) v = *(const float4*)(A + (size_t)(n0 + r) * lda + kc + k4);
      pa[u] = v;
    }
  };
  auto loadW = [&](int kc) {
    #pragma unroll
    for (int u = 0; u < 4; ++u) {
      const int i = tid + 256 * u;
      const int k = i >> 5, c = (i & 31) << 2;
      pw[u] = *(const float4*)(W + (size_t)(kc + k) * 128 + c);
    }
  };
  auto stage = [&]() {
    #pragma unroll
    for (int u = 0; u < 4; ++u) {
      const int i = tid + 256 * u;
      const int r = i >> 3, k4 = (i & 7) << 2;
      const int c = r ^ k4;  // k4 in {0..28}
      hsT[k4 + 0][c] = pa[u].x; hsT[k4 + 1][c] = pa[u].y;
      hsT[k4 + 2][c] = pa[u].z; hsT[k4 + 3][c] = pa[u].w;
      const int k = i >> 5, wc = (i & 31) << 2;
      Ws[k][wc] = pw[u].x; Ws[k][wc + 1] = pw[u].y;
      Ws[k][wc + 2] = pw[u].z; Ws[k][wc + 3] = pw[u].w;
    }
  };

  loadA(0); loadW(0);
  for (int kc = 0; kc < 128; kc += 32) {
    stage();
    __syncthreads();
    if (kc + 32 < 128) { loadA(kc + 32); loadW(kc + 32); }  // overlap w/ compute
    #pragma unroll
    for (int k = 0; k < 32; ++k) {
      const int s = k & 28;
      const float4 a0 = *(const float4*)&hsT[k][tr ^ s];
      const float4 a1 = *(const float4*)&hsT[k][(tr + 4) ^ s];
      const float4 w0 = *(const float4*)&Ws[k][tc];
      const float4 w1 = *(const float4*)&Ws[k][tc + 4];
      const float a[8] = {a0.x, a0.y, a0.z, a0.w, a1.x, a1.y, a1.z, a1.w};
      const float w[8] = {w0.x, w0.y, w0.z, w0.w, w1.x, w1.y, w1.z, w1.w};
      #pragma unroll
      for (int i = 0; i < 8; ++i)
        #pragma unroll
        for (int j = 0; j < 8; ++j) acc[i][j] = fmaf(a[i], w[j], acc[i][j]);
    }
    __syncthreads();
  }

  #pragma unroll
  for (int i = 0; i < 8; ++i) {
    const int r = tr + i;
    if (r < rows) {
      const int n = n0 + r;
      const float dv = dinv[n];
      float* hwp = hw + (size_t)n * 128 + tc;
      *(float4*)(hwp + 0) = make_float4(acc[i][0] * dv, acc[i][1] * dv,
                                        acc[i][2] * dv, acc[i][3] * dv);
      *(float4*)(hwp + 4) = make_float4(acc[i][4] * dv, acc[i][5] * dv,
                                        acc[i][6] * dv, acc[i][7] * dv);
    }
  }
}

// ---- segment aggregate: hcat[n] = relu(dinv[n]*(hw[n]+sum hw[r]) + b) -----
// one 32-lane group per node, lane owns 4 features; hw pre-scaled by dinv
__global__ __launch_bounds__(256) void k_agg(
    const int* __restrict__ offs, const int* __restrict__ degi,
    const int* __restrict__ sorted_row, const float* __restrict__ dinv,
    const float* __restrict__ hw, const float* __restrict__ bias,
    float* __restrict__ hcat, int koff, int N) {
  const int g = (int)((blockIdx.x * 256 + threadIdx.x) >> 5);
  if (g >= N) return;
  const int j = (threadIdx.x & 31) << 2;
  float4 acc = *(const float4*)(hw + (size_t)g * 128 + j);  // self term

  const int off = offs[g];
  const int end = off + degi[g];
  int e = off;
  for (; e + 7 < end; e += 8) {  // 8 gathers in flight
    int r[8];
    #pragma unroll
    for (int t = 0; t < 8; ++t) r[t] = sorted_row[e + t];
    float4 v[8];
    #pragma unroll
    for (int t = 0; t < 8; ++t) v[t] = *(const float4*)(hw + (size_t)r[t] * 128 + j);
    #pragma unroll
    for (int t = 0; t < 8; ++t) {
      acc.x += v[t].x; acc.y += v[t].y; acc.z += v[t].z; acc.w += v[t].w;
    }
  }
  for (; e + 3 < end; e += 4) {
    int r[4];
    #pragma unroll
    for (int t = 0; t < 4; ++t) r[t] = sorted_row[e + t];
    float4 v[4];
    #pragma unroll
    for (int t = 0; t < 4; ++t) v[t] = *(const float4*)(hw + (size_t)r[t] * 128 + j);
    #pragma unroll
    for (int t = 0; t < 4; ++t) {
      acc.x += v[t].x; acc.y += v[t].y; acc.z += v[t].z; acc.w += v[t].w;
    }
  }
  for (; e < end; ++e) {
    const int r0 = sorted_row[e];
    const float4 v0 = *(const float4*)(hw + (size_t)r0 * 128 + j);
    acc.x += v0.x; acc.y += v0.y; acc.z += v0.z; acc.w += v0.w;
  }
  const float dc = dinv[g];
  const float4 bb = *(const float4*)(bias + j);
  *(float4*)(hcat + (size_t)g * 384 + koff + j) =
      make_float4(fmaxf(fmaf(dc, acc.x, bb.x), 0.f),
                  fmaxf(fmaf(dc, acc.y, bb.y), 0.f),
                  fmaxf(fmaf(dc, acc.z, bb.z), 0.f),
                  fmaxf(fmaf(dc, acc.w, bb.w), 0.f));
}

// ---- final: out = hcat @ Wlin + blin, K=384, 12 chunks of 32 --------------
// (256,4): VGPR cap 128, need ~80 (acc 32 + pa/pw 24 + addressing). No spill.
__global__ __launch_bounds__(256, 4) void k_final(
    const float* __restrict__ hcat, const float* __restrict__ Wlin,
    const float* __restrict__ blin, float* __restrict__ out, int N) {
  __shared__ __align__(16) float hsT[32][128];  // 16KB
  __shared__ __align__(16) float Ws[32][64];    // 8KB
  const int tid = threadIdx.x;
  const int n0 = blockIdx.x * 128;
  const int rows = min(128, N - n0);
  const int tc = (tid & 15) << 2;
  const int tr = (tid >> 4) << 3;
  float acc[8][4] = {};
  float4 pa[4], pw[2];

  auto loadA = [&](int kc) {
    #pragma unroll
    for (int u = 0; u < 4; ++u) {
      const int i = tid + 256 * u;
      const int r = i >> 3, k4 = (i & 7) << 2;
      float4 v = make_float4(0.f, 0.f, 0.f, 0.f);
      if (r < rows) v = *(const float4*)(hcat + (size_t)(n0 + r) * 384 + kc + k4);
      pa[u] = v;
    }
  };
  auto loadW = [&](int kc) {
    #pragma unroll
    for (int u = 0; u < 2; ++u) {
      const int i = tid + 256 * u;
      const int k = i >> 4, c = (i & 15) << 2;
      pw[u] = *(const float4*)(Wlin + (size_t)(kc + k) * 64 + c);
    }
  };
  auto stage = [&]() {
    #pragma unroll
    for (int u = 0; u < 4; ++u) {
      const int i = tid + 256 * u;
      const int r = i >> 3, k4 = (i & 7) << 2;
      const int c = r ^ k4;
      hsT[k4 + 0][c] = pa[u].x; hsT[k4 + 1][c] = pa[u].y;
      hsT[k4 + 2][c] = pa[u].z; hsT[k4 + 3][c] = pa[u].w;
    }
    #pragma unroll
    for (int u = 0; u < 2; ++u) {
      const int i = tid + 256 * u;
      const int k = i >> 4, c = (i & 15) << 2;
      Ws[k][c] = pw[u].x; Ws[k][c + 1] = pw[u].y;
      Ws[k][c + 2] = pw[u].z; Ws[k][c + 3] = pw[u].w;
    }
  };

  loadA(0); loadW(0);
  for (int kc = 0; kc < 384; kc += 32) {
    stage();
    __syncthreads();
    if (kc + 32 < 384) { loadA(kc + 32); loadW(kc + 32); }  // overlap w/ compute
    #pragma unroll
    for (int k = 0; k < 32; ++k) {
      const int s = k & 28;
      const float4 a0 = *(const float4*)&hsT[k][tr ^ s];
      const float4 a1 = *(const float4*)&hsT[k][(tr + 4) ^ s];
      const float4 w0 = *(const float4*)&Ws[k][tc];
      const float a[8] = {a0.x, a0.y, a0.z, a0.w, a1.x, a1.y, a1.z, a1.w};
      const float w[4] = {w0.x, w0.y, w0.z, w0.w};
      #pragma unroll
      for (int i = 0; i < 8; ++i)
        #pragma unroll
        for (int j = 0; j < 4; ++j) acc[i][j] = fmaf(a[i], w[j], acc[i][j]);
    }
    __syncthreads();
  }

  #pragma unroll
  for (int i = 0; i < 8; ++i) {
    const int r = tr + i;
    if (r < rows) {
      const float4 bb = *(const float4*)(blin + tc);
      *(float4*)(out + (size_t)(n0 + r) * 64 + tc) =
          make_float4(acc[i][0] + bb.x, acc[i][1] + bb.y,
                      acc[i][2] + bb.z, acc[i][3] + bb.w);
    }
  }
}

extern "C" void kernel_launch(void* const* d_in, const int* in_sizes, int n_in,
                              void* d_out, int out_size, void* d_ws, size_t ws_size,
                              hipStream_t stream) {
  const float* x    = (const float*)d_in[0];
  const int*   ei   = (const int*)d_in[1];
  const float* W1   = (const float*)d_in[2];
  const float* b1   = (const float*)d_in[3];
  const float* W2   = (const float*)d_in[4];
  const float* b2   = (const float*)d_in[5];
  const float* W3   = (const float*)d_in[6];
  const float* b3   = (const float*)d_in[7];
  const float* Wlin = (const float*)d_in[8];
  const float* blin = (const float*)d_in[9];

  const int N = in_sizes[0] / 128;
  const int E = in_sizes[1] / 2;
  const int* rowi = ei;
  const int* coli = ei + E;

  // ws layout: degi | dinv | offs | cursor | bsums | sorted_row | hw | hcat
  char* ws = (char*)d_ws;
  const size_t nb4 = (((size_t)N * 4) + 255) & ~(size_t)255;
  int*   degi       = (int*)ws;                 ws += nb4;
  float* dinv       = (float*)ws;               ws += nb4;
  int*   offs       = (int*)ws;                 ws += nb4;
  int*   cursor     = (int*)ws;                 ws += nb4;
  int*   bsums      = (int*)ws;                 ws += 1024;
  int*   sorted_row = (int*)ws;                 ws += (((size_t)E * 4) + 255) & ~(size_t)255;
  float* hw         = (float*)ws;               ws += (size_t)N * 128 * 4;
  float* hcat       = (float*)ws;

  const int nblk = (N + 1023) / 1024;  // <= 128 for N <= 131072

  hipMemsetAsync(degi, 0, (size_t)N * 4, stream);
  k_deg  <<<(E + 255) / 256, 256, 0, stream>>>(coli, E, degi);
  k_dinv <<<(N + 255) / 256, 256, 0, stream>>>(degi, dinv, N);
  k_scan1<<<nblk, 256, 0, stream>>>(degi, N, offs, bsums);
  k_scan2<<<1, 128, 0, stream>>>(bsums, nblk);
  k_scan3<<<nblk, 256, 0, stream>>>(offs, bsums, cursor, N);
  k_fill <<<(E + 255) / 256, 256, 0, stream>>>(rowi, coli, E, cursor, sorted_row);

  const float* Wk[3] = {W1, W2, W3};
  const float* bk[3] = {b1, b2, b3};
  const int gemmBlocks = (N + 127) / 128;
  const int aggBlocks  = (N + 7) / 8;

  const float* Ain = x;
  long long lda = 128;
  for (int k = 0; k < 3; ++k) {
    k_gemm128<<<gemmBlocks, 256, 0, stream>>>(Ain, lda, Wk[k], dinv, hw, N);
    k_agg<<<aggBlocks, 256, 0, stream>>>(offs, degi, sorted_row, dinv, hw,
                                         bk[k], hcat, k * 128, N);
    Ain = hcat + k * 128;
    lda = 384;
  }
  k_final<<<gemmBlocks, 256, 0, stream>>>(hcat, Wlin, blin, (float*)d_out, N);
}

// Round 6
// 806.124 us; speedup vs baseline: 1.4494x; 1.4494x over previous
//
#include <hip/hip_runtime.h>
#include <hip/hip_bf16.h>

// ---------------------------------------------------------------------------
// GCN via device-built CSR (no f32 atomics):
//   deg -> exclusive scan -> bucket fill sorted_row[]
//   3x [ hw = dinv * (hprev @ W) ;
//        hcat_k[n] = relu(dinv[n]*(hw[n] + sum_in hw[r]) + b) ]  (post-relu)
//   out = hcat @ Wlin + blin
// GEMMs: K=32 LDS chunks, A-stream reg prefetch, W staged direct to LDS.
// __launch_bounds__(256,2): this compiler caps VGPR at ~256/arg -> arg 2 =
// 128-reg cap = spill-free here (arg>=3 caused 230MB+ of scratch traffic).
// Microtile cols split into two contiguous float4 groups (tc4, tc4+64) so
// each Ws read covers 256B/wave across all 32 banks (0 conflicts).
// ---------------------------------------------------------------------------

// ---- degree count: deg[col]++ ---------------------------------------------
__global__ __launch_bounds__(256) void k_deg(const int* __restrict__ col, int E,
                                             int* __restrict__ degi) {
  int e = blockIdx.x * 256 + threadIdx.x;
  if (e < E) atomicAdd(&degi[col[e]], 1);
}

// ---- dinv = rsqrt(1 + deg) ------------------------------------------------
__global__ __launch_bounds__(256) void k_dinv(const int* __restrict__ degi,
                                              float* __restrict__ dinv, int N) {
  int n = blockIdx.x * 256 + threadIdx.x;
  if (n < N) dinv[n] = rsqrtf(1.0f + (float)degi[n]);
}

// ---- scan pass 1: per-1024-chunk exclusive scan + block sums --------------
__global__ __launch_bounds__(256) void k_scan1(const int* __restrict__ degi, int N,
                                               int* __restrict__ offs,
                                               int* __restrict__ bsums) {
  __shared__ int sm[256];
  const int b = blockIdx.x, t = threadIdx.x;
  const int base = b * 1024 + t * 4;
  int v[4];
  #pragma unroll
  for (int i = 0; i < 4; ++i) v[i] = (base + i < N) ? degi[base + i] : 0;
  const int s = v[0] + v[1] + v[2] + v[3];
  sm[t] = s;
  __syncthreads();
  for (int ofs = 1; ofs < 256; ofs <<= 1) {
    const int add = (t >= ofs) ? sm[t - ofs] : 0;
    __syncthreads();
    sm[t] += add;
    __syncthreads();
  }
  if (t == 255) bsums[b] = sm[255];
  int run = sm[t] - s;
  #pragma unroll
  for (int i = 0; i < 4; ++i) {
    if (base + i < N) offs[base + i] = run;
    run += v[i];
  }
}

// ---- scan pass 2: exclusive scan of block sums (nb <= 128) ----------------
__global__ __launch_bounds__(128) void k_scan2(int* __restrict__ bsums, int nb) {
  __shared__ int sm[128];
  const int t = threadIdx.x;
  const int v = (t < nb) ? bsums[t] : 0;
  sm[t] = v;
  __syncthreads();
  for (int ofs = 1; ofs < 128; ofs <<= 1) {
    const int add = (t >= ofs) ? sm[t - ofs] : 0;
    __syncthreads();
    sm[t] += add;
    __syncthreads();
  }
  if (t < nb) bsums[t] = sm[t] - v;
}

// ---- scan pass 3: add block offset; copy to cursor ------------------------
__global__ __launch_bounds__(256) void k_scan3(int* __restrict__ offs,
                                               const int* __restrict__ bsums,
                                               int* __restrict__ cursor, int N) {
  const int add = bsums[blockIdx.x];
  const int base = blockIdx.x * 1024 + threadIdx.x * 4;
  #pragma unroll
  for (int i = 0; i < 4; ++i) {
    const int idx = base + i;
    if (idx < N) {
      const int o = offs[idx] + add;
      offs[idx] = o;
      cursor[idx] = o;
    }
  }
}

// ---- bucket fill: sorted_row[pos] = row ------------------------------------
__global__ __launch_bounds__(256) void k_fill(const int* __restrict__ rowi,
                                              const int* __restrict__ coli, int E,
                                              int* __restrict__ cursor,
                                              int* __restrict__ sorted_row) {
  int e = blockIdx.x * 256 + threadIdx.x;
  if (e < E) {
    const int pos = atomicAdd(&cursor[coli[e]], 1);
    sorted_row[pos] = rowi[e];
  }
}

// ---- layer GEMM: hw = dinv * (A @ W), K=128, 4 chunks of 32 ---------------
// VGPR need ~110 (acc 64 + pa 16 + addressing) <= 128 cap. No spill.
__global__ __launch_bounds__(256, 2) void k_gemm128(
    const float* __restrict__ A, long long lda,
    const float* __restrict__ W, const float* __restrict__ dinv,
    float* __restrict__ hw, int N) {
  __shared__ __align__(16) float hsT[32][128];  // [k][r ^ (k&28)]
  __shared__ __align__(16) float Ws[32][128];   // [k][c]
  const int tid = threadIdx.x;
  const int n0 = blockIdx.x * 128;
  const int rows = min(128, N - n0);
  const int tc4 = (tid & 15) << 2;   // col group 1: tc4..tc4+3; group 2: +64
  const int tr = (tid >> 4) << 3;    // 8 rows
  float acc[8][8] = {};
  float4 pa[4];

  auto loadA = [&](int kc) {
    #pragma unroll
    for (int u = 0; u < 4; ++u) {
      const int i = tid + 256 * u;
      const int r = i >> 3, k4 = (i & 7) << 2;
      float4 v = make_float4(0.f, 0.f, 0.f, 0.f);
      if (r < rows) v = *(const float4*)(A + (size_t)(n0 + r) * lda + kc + k4);
      pa[u] = v;
    }
  };
  auto stageA = [&]() {
    #pragma unroll
    for (int u = 0; u < 4; ++u) {
      const int i = tid + 256 * u;
      const int r = i >> 3, k4 = (i & 7) << 2;
      const int c = r ^ k4;  // k4 in {0..28}
      hsT[k4 + 0][c] = pa[u].x; hsT[k4 + 1][c] = pa[u].y;
      hsT[k4 + 2][c] = pa[u].z; hsT[k4 + 3][c] = pa[u].w;
    }
  };
  auto stageW = [&](int kc) {  // direct global->LDS (L2-hot, low pressure)
    #pragma unroll
    for (int u = 0; u < 4; ++u) {
      const int i = tid + 256 * u;
      const int k = i >> 5, c = (i & 31) << 2;
      *(float4*)&Ws[k][c] = *(const float4*)(W + (size_t)(kc + k) * 128 + c);
    }
  };

  loadA(0);
  for (int kc = 0; kc < 128; kc += 32) {
    stageW(kc);
    stageA();
    __syncthreads();
    if (kc + 32 < 128) loadA(kc + 32);  // prefetch next A chunk into regs
    #pragma unroll
    for (int k = 0; k < 32; ++k) {
      const int s = k & 28;
      const float4 a0 = *(const float4*)&hsT[k][tr ^ s];
      const float4 a1 = *(const float4*)&hsT[k][(tr + 4) ^ s];
      const float4 w0 = *(const float4*)&Ws[k][tc4];        // 256B/wave, no conflict
      const float4 w1 = *(const float4*)&Ws[k][tc4 + 64];   // 256B/wave, no conflict
      const float a[8] = {a0.x, a0.y, a0.z, a0.w, a1.x, a1.y, a1.z, a1.w};
      const float w[8] = {w0.x, w0.y, w0.z, w0.w, w1.x, w1.y, w1.z, w1.w};
      #pragma unroll
      for (int i = 0; i < 8; ++i)
        #pragma unroll
        for (int j = 0; j < 8; ++j) acc[i][j] = fmaf(a[i], w[j], acc[i][j]);
    }
    __syncthreads();
  }

  #pragma unroll
  for (int i = 0; i < 8; ++i) {
    const int r = tr + i;
    if (r < rows) {
      const int n = n0 + r;
      const float dv = dinv[n];
      float* hwp = hw + (size_t)n * 128;
      *(float4*)(hwp + tc4) = make_float4(acc[i][0] * dv, acc[i][1] * dv,
                                          acc[i][2] * dv, acc[i][3] * dv);
      *(float4*)(hwp + tc4 + 64) = make_float4(acc[i][4] * dv, acc[i][5] * dv,
                                               acc[i][6] * dv, acc[i][7] * dv);
    }
  }
}

// ---- segment aggregate: hcat[n] = relu(dinv[n]*(hw[n]+sum hw[r]) + b) -----
// one 32-lane group per node, lane owns 4 features; hw pre-scaled by dinv
__global__ __launch_bounds__(256) void k_agg(
    const int* __restrict__ offs, const int* __restrict__ degi,
    const int* __restrict__ sorted_row, const float* __restrict__ dinv,
    const float* __restrict__ hw, const float* __restrict__ bias,
    float* __restrict__ hcat, int koff, int N) {
  const int g = (int)((blockIdx.x * 256 + threadIdx.x) >> 5);
  if (g >= N) return;
  const int j = (threadIdx.x & 31) << 2;
  float4 acc = *(const float4*)(hw + (size_t)g * 128 + j);  // self term

  const int off = offs[g];
  const int end = off + degi[g];
  int e = off;
  for (; e + 7 < end; e += 8) {  // 8 gathers in flight
    int r[8];
    #pragma unroll
    for (int t = 0; t < 8; ++t) r[t] = sorted_row[e + t];
    float4 v[8];
    #pragma unroll
    for (int t = 0; t < 8; ++t) v[t] = *(const float4*)(hw + (size_t)r[t] * 128 + j);
    #pragma unroll
    for (int t = 0; t < 8; ++t) {
      acc.x += v[t].x; acc.y += v[t].y; acc.z += v[t].z; acc.w += v[t].w;
    }
  }
  for (; e + 3 < end; e += 4) {
    int r[4];
    #pragma unroll
    for (int t = 0; t < 4; ++t) r[t] = sorted_row[e + t];
    float4 v[4];
    #pragma unroll
    for (int t = 0; t < 4; ++t) v[t] = *(const float4*)(hw + (size_t)r[t] * 128 + j);
    #pragma unroll
    for (int t = 0; t < 4; ++t) {
      acc.x += v[t].x; acc.y += v[t].y; acc.z += v[t].z; acc.w += v[t].w;
    }
  }
  for (; e < end; ++e) {
    const int r0 = sorted_row[e];
    const float4 v0 = *(const float4*)(hw + (size_t)r0 * 128 + j);
    acc.x += v0.x; acc.y += v0.y; acc.z += v0.z; acc.w += v0.w;
  }
  const float dc = dinv[g];
  const float4 bb = *(const float4*)(bias + j);
  *(float4*)(hcat + (size_t)g * 384 + koff + j) =
      make_float4(fmaxf(fmaf(dc, acc.x, bb.x), 0.f),
                  fmaxf(fmaf(dc, acc.y, bb.y), 0.f),
                  fmaxf(fmaf(dc, acc.z, bb.z), 0.f),
                  fmaxf(fmaf(dc, acc.w, bb.w), 0.f));
}

// ---- final: out = hcat @ Wlin + blin, K=384, 12 chunks of 32 --------------
// VGPR need ~75 (acc 32 + pa 16 + addressing) <= 128 cap. No spill.
__global__ __launch_bounds__(256, 2) void k_final(
    const float* __restrict__ hcat, const float* __restrict__ Wlin,
    const float* __restrict__ blin, float* __restrict__ out, int N) {
  __shared__ __align__(16) float hsT[32][128];  // 16KB
  __shared__ __align__(16) float Ws[32][64];    // 8KB
  const int tid = threadIdx.x;
  const int n0 = blockIdx.x * 128;
  const int rows = min(128, N - n0);
  const int tc = (tid & 15) << 2;
  const int tr = (tid >> 4) << 3;
  float acc[8][4] = {};
  float4 pa[4];

  auto loadA = [&](int kc) {
    #pragma unroll
    for (int u = 0; u < 4; ++u) {
      const int i = tid + 256 * u;
      const int r = i >> 3, k4 = (i & 7) << 2;
      float4 v = make_float4(0.f, 0.f, 0.f, 0.f);
      if (r < rows) v = *(const float4*)(hcat + (size_t)(n0 + r) * 384 + kc + k4);
      pa[u] = v;
    }
  };
  auto stageA = [&]() {
    #pragma unroll
    for (int u = 0; u < 4; ++u) {
      const int i = tid + 256 * u;
      const int r = i >> 3, k4 = (i & 7) << 2;
      const int c = r ^ k4;
      hsT[k4 + 0][c] = pa[u].x; hsT[k4 + 1][c] = pa[u].y;
      hsT[k4 + 2][c] = pa[u].z; hsT[k4 + 3][c] = pa[u].w;
    }
  };
  auto stageW = [&](int kc) {
    #pragma unroll
    for (int u = 0; u < 2; ++u) {
      const int i = tid + 256 * u;
      const int k = i >> 4, c = (i & 15) << 2;
      *(float4*)&Ws[k][c] = *(const float4*)(Wlin + (size_t)(kc + k) * 64 + c);
    }
  };

  loadA(0);
  for (int kc = 0; kc < 384; kc += 32) {
    stageW(kc);
    stageA();
    __syncthreads();
    if (kc + 32 < 384) loadA(kc + 32);
    #pragma unroll
    for (int k = 0; k < 32; ++k) {
      const int s = k & 28;
      const float4 a0 = *(const float4*)&hsT[k][tr ^ s];
      const float4 a1 = *(const float4*)&hsT[k][(tr + 4) ^ s];
      const float4 w0 = *(const float4*)&Ws[k][tc];
      const float a[8] = {a0.x, a0.y, a0.z, a0.w, a1.x, a1.y, a1.z, a1.w};
      const float w[4] = {w0.x, w0.y, w0.z, w0.w};
      #pragma unroll
      for (int i = 0; i < 8; ++i)
        #pragma unroll
        for (int j = 0; j < 4; ++j) acc[i][j] = fmaf(a[i], w[j], acc[i][j]);
    }
    __syncthreads();
  }

  #pragma unroll
  for (int i = 0; i < 8; ++i) {
    const int r = tr + i;
    if (r < rows) {
      const float4 bb = *(const float4*)(blin + tc);
      *(float4*)(out + (size_t)(n0 + r) * 64 + tc) =
          make_float4(acc[i][0] + bb.x, acc[i][1] + bb.y,
                      acc[i][2] + bb.z, acc[i][3] + bb.w);
    }
  }
}

extern "C" void kernel_launch(void* const* d_in, const int* in_sizes, int n_in,
                              void* d_out, int out_size, void* d_ws, size_t ws_size,
                              hipStream_t stream) {
  const float* x    = (const float*)d_in[0];
  const int*   ei   = (const int*)d_in[1];
  const float* W1   = (const float*)d_in[2];
  const float* b1   = (const float*)d_in[3];
  const float* W2   = (const float*)d_in[4];
  const float* b2   = (const float*)d_in[5];
  const float* W3   = (const float*)d_in[6];
  const float* b3   = (const float*)d_in[7];
  const float* Wlin = (const float*)d_in[8];
  const float* blin = (const float*)d_in[9];

  const int N = in_sizes[0] / 128;
  const int E = in_sizes[1] / 2;
  const int* rowi = ei;
  const int* coli = ei + E;

  // ws layout: degi | dinv | offs | cursor | bsums | sorted_row | hw | hcat
  char* ws = (char*)d_ws;
  const size_t nb4 = (((size_t)N * 4) + 255) & ~(size_t)255;
  int*   degi       = (int*)ws;                 ws += nb4;
  float* dinv       = (float*)ws;               ws += nb4;
  int*   offs       = (int*)ws;                 ws += nb4;
  int*   cursor     = (int*)ws;                 ws += nb4;
  int*   bsums      = (int*)ws;                 ws += 1024;
  int*   sorted_row = (int*)ws;                 ws += (((size_t)E * 4) + 255) & ~(size_t)255;
  float* hw         = (float*)ws;               ws += (size_t)N * 128 * 4;
  float* hcat       = (float*)ws;

  const int nblk = (N + 1023) / 1024;  // <= 128 for N <= 131072

  hipMemsetAsync(degi, 0, (size_t)N * 4, stream);
  k_deg  <<<(E + 255) / 256, 256, 0, stream>>>(coli, E, degi);
  k_dinv <<<(N + 255) / 256, 256, 0, stream>>>(degi, dinv, N);
  k_scan1<<<nblk, 256, 0, stream>>>(degi, N, offs, bsums);
  k_scan2<<<1, 128, 0, stream>>>(bsums, nblk);
  k_scan3<<<nblk, 256, 0, stream>>>(offs, bsums, cursor, N);
  k_fill <<<(E + 255) / 256, 256, 0, stream>>>(rowi, coli, E, cursor, sorted_row);

  const float* Wk[3] = {W1, W2, W3};
  const float* bk[3] = {b1, b2, b3};
  const int gemmBlocks = (N + 127) / 128;
  const int aggBlocks  = (N + 7) / 8;

  const float* Ain = x;
  long long lda = 128;
  for (int k = 0; k < 3; ++k) {
    k_gemm128<<<gemmBlocks, 256, 0, stream>>>(Ain, lda, Wk[k], dinv, hw, N);
    k_agg<<<aggBlocks, 256, 0, stream>>>(offs, degi, sorted_row, dinv, hw,
                                         bk[k], hcat, k * 128, N);
    Ain = hcat + k * 128;
    lda = 384;
  }
  k_final<<<gemmBlocks, 256, 0, stream>>>(hcat, Wlin, blin, (float*)d_out, N);
}

// Round 7
// 737.248 us; speedup vs baseline: 1.5848x; 1.0934x over previous
//
#include <hip/hip_runtime.h>
#include <hip/hip_bf16.h>

// ---------------------------------------------------------------------------
// GCN via device-built CSR (no f32 atomics):
//   mega0 = [gemm1 lower half | deg count]   (independent -> co-scheduled)
//   scan(+dinv) ; mega1 = [gemm1 upper half | CSR bucket fill]
//   3x [ hw = hprev @ W (raw) ;
//        hcat_k[n] = relu(dinv_n*(dinv_n*hw[n] + sum_in dinv_r*hw[r]) + b) ]
//   out = hcat @ Wlin + blin
// GEMMs: K=32 LDS chunks, A-stream reg prefetch, W direct to LDS,
// __launch_bounds__(256,2) = 128-VGPR cap = spill-free (arg>=3 spills).
// ---------------------------------------------------------------------------

// ---- shared GEMM-128 body (A [N x lda] @ W [128x128] -> hw raw) -----------
__device__ __forceinline__ void gemm128_body(
    const float* __restrict__ A, long long lda,
    const float* __restrict__ W, float* __restrict__ hw, int N, int n0,
    float (*hsT)[128], float (*Ws)[128]) {
  const int tid = threadIdx.x;
  const int rows = min(128, N - n0);
  const int tc4 = (tid & 15) << 2;   // col group 1: tc4..+3; group 2: +64
  const int tr = (tid >> 4) << 3;    // 8 rows
  float acc[8][8] = {};
  float4 pa[4];

  auto loadA = [&](int kc) {
    #pragma unroll
    for (int u = 0; u < 4; ++u) {
      const int i = tid + 256 * u;
      const int r = i >> 3, k4 = (i & 7) << 2;
      float4 v = make_float4(0.f, 0.f, 0.f, 0.f);
      if (r < rows) v = *(const float4*)(A + (size_t)(n0 + r) * lda + kc + k4);
      pa[u] = v;
    }
  };
  auto stageA = [&]() {
    #pragma unroll
    for (int u = 0; u < 4; ++u) {
      const int i = tid + 256 * u;
      const int r = i >> 3, k4 = (i & 7) << 2;
      const int c = r ^ k4;  // k4 in {0..28}
      hsT[k4 + 0][c] = pa[u].x; hsT[k4 + 1][c] = pa[u].y;
      hsT[k4 + 2][c] = pa[u].z; hsT[k4 + 3][c] = pa[u].w;
    }
  };
  auto stageW = [&](int kc) {  // direct global->LDS (L2-hot)
    #pragma unroll
    for (int u = 0; u < 4; ++u) {
      const int i = tid + 256 * u;
      const int k = i >> 5, c = (i & 31) << 2;
      *(float4*)&Ws[k][c] = *(const float4*)(W + (size_t)(kc + k) * 128 + c);
    }
  };

  loadA(0);
  for (int kc = 0; kc < 128; kc += 32) {
    stageW(kc);
    stageA();
    __syncthreads();
    if (kc + 32 < 128) loadA(kc + 32);  // prefetch next A chunk into regs
    #pragma unroll
    for (int k = 0; k < 32; ++k) {
      const int s = k & 28;
      const float4 a0 = *(const float4*)&hsT[k][tr ^ s];
      const float4 a1 = *(const float4*)&hsT[k][(tr + 4) ^ s];
      const float4 w0 = *(const float4*)&Ws[k][tc4];        // 256B/wave
      const float4 w1 = *(const float4*)&Ws[k][tc4 + 64];   // 256B/wave
      const float a[8] = {a0.x, a0.y, a0.z, a0.w, a1.x, a1.y, a1.z, a1.w};
      const float w[8] = {w0.x, w0.y, w0.z, w0.w, w1.x, w1.y, w1.z, w1.w};
      #pragma unroll
      for (int i = 0; i < 8; ++i)
        #pragma unroll
        for (int j = 0; j < 8; ++j) acc[i][j] = fmaf(a[i], w[j], acc[i][j]);
    }
    __syncthreads();
  }

  #pragma unroll
  for (int i = 0; i < 8; ++i) {
    const int r = tr + i;
    if (r < rows) {
      float* hwp = hw + (size_t)(n0 + r) * 128;
      *(float4*)(hwp + tc4) = make_float4(acc[i][0], acc[i][1], acc[i][2], acc[i][3]);
      *(float4*)(hwp + tc4 + 64) = make_float4(acc[i][4], acc[i][5], acc[i][6], acc[i][7]);
    }
  }
}

// ---- mega0: [gemm1 lower | degree count] ----------------------------------
__global__ __launch_bounds__(256, 2) void k_mega0(
    const float* __restrict__ x, const float* __restrict__ W1,
    float* __restrict__ hw, int N, int gb,
    const int* __restrict__ coli, int E, int* __restrict__ degi) {
  __shared__ __align__(16) float hsT[32][128];
  __shared__ __align__(16) float Ws[32][128];
  if ((int)blockIdx.x < gb) {
    gemm128_body(x, 128, W1, hw, N, blockIdx.x * 128, hsT, Ws);
  } else {
    const int b = blockIdx.x - gb;
    #pragma unroll
    for (int h = 0; h < 2; ++h) {
      const int base = b * 2048 + h * 1024 + (int)threadIdx.x * 4;
      if (base + 3 < E) {
        const int4 c4 = *(const int4*)(coli + base);
        atomicAdd(&degi[c4.x], 1); atomicAdd(&degi[c4.y], 1);
        atomicAdd(&degi[c4.z], 1); atomicAdd(&degi[c4.w], 1);
      } else {
        for (int e = base; e < E; ++e) atomicAdd(&degi[coli[e]], 1);
      }
    }
  }
}

// ---- mega1: [gemm1 upper | CSR bucket fill] -------------------------------
__global__ __launch_bounds__(256, 2) void k_mega1(
    const float* __restrict__ x, const float* __restrict__ W1,
    float* __restrict__ hw, int N, int gb, int goff,
    const int* __restrict__ rowi, const int* __restrict__ coli,
    int* __restrict__ cursor, int* __restrict__ sorted_row, int E) {
  __shared__ __align__(16) float hsT[32][128];
  __shared__ __align__(16) float Ws[32][128];
  if ((int)blockIdx.x < gb) {
    gemm128_body(x, 128, W1, hw, N, (goff + blockIdx.x) * 128, hsT, Ws);
  } else {
    const int b = blockIdx.x - gb;
    const int base = b * 1024 + (int)threadIdx.x * 4;
    if (base + 3 < E) {
      const int4 c4 = *(const int4*)(coli + base);
      const int4 r4 = *(const int4*)(rowi + base);
      int p;
      p = atomicAdd(&cursor[c4.x], 1); sorted_row[p] = r4.x;
      p = atomicAdd(&cursor[c4.y], 1); sorted_row[p] = r4.y;
      p = atomicAdd(&cursor[c4.z], 1); sorted_row[p] = r4.z;
      p = atomicAdd(&cursor[c4.w], 1); sorted_row[p] = r4.w;
    } else {
      for (int e = base; e < E; ++e) {
        const int p = atomicAdd(&cursor[coli[e]], 1);
        sorted_row[p] = rowi[e];
      }
    }
  }
}

// ---- scan pass 1: per-1024-chunk exclusive scan + block sums + dinv -------
__global__ __launch_bounds__(256) void k_scan1(const int* __restrict__ degi, int N,
                                               int* __restrict__ offs,
                                               int* __restrict__ bsums,
                                               float* __restrict__ dinv) {
  __shared__ int sm[256];
  const int b = blockIdx.x, t = threadIdx.x;
  const int base = b * 1024 + t * 4;
  int v[4];
  #pragma unroll
  for (int i = 0; i < 4; ++i) v[i] = (base + i < N) ? degi[base + i] : 0;
  #pragma unroll
  for (int i = 0; i < 4; ++i)
    if (base + i < N) dinv[base + i] = rsqrtf(1.0f + (float)v[i]);
  const int s = v[0] + v[1] + v[2] + v[3];
  sm[t] = s;
  __syncthreads();
  for (int ofs = 1; ofs < 256; ofs <<= 1) {
    const int add = (t >= ofs) ? sm[t - ofs] : 0;
    __syncthreads();
    sm[t] += add;
    __syncthreads();
  }
  if (t == 255) bsums[b] = sm[255];
  int run = sm[t] - s;
  #pragma unroll
  for (int i = 0; i < 4; ++i) {
    if (base + i < N) offs[base + i] = run;
    run += v[i];
  }
}

// ---- scan pass 2: exclusive scan of block sums (nb <= 128) ----------------
__global__ __launch_bounds__(128) void k_scan2(int* __restrict__ bsums, int nb) {
  __shared__ int sm[128];
  const int t = threadIdx.x;
  const int v = (t < nb) ? bsums[t] : 0;
  sm[t] = v;
  __syncthreads();
  for (int ofs = 1; ofs < 128; ofs <<= 1) {
    const int add = (t >= ofs) ? sm[t - ofs] : 0;
    __syncthreads();
    sm[t] += add;
    __syncthreads();
  }
  if (t < nb) bsums[t] = sm[t] - v;
}

// ---- scan pass 3: add block offset; copy to cursor ------------------------
__global__ __launch_bounds__(256) void k_scan3(int* __restrict__ offs,
                                               const int* __restrict__ bsums,
                                               int* __restrict__ cursor, int N) {
  const int add = bsums[blockIdx.x];
  const int base = blockIdx.x * 1024 + threadIdx.x * 4;
  #pragma unroll
  for (int i = 0; i < 4; ++i) {
    const int idx = base + i;
    if (idx < N) {
      const int o = offs[idx] + add;
      offs[idx] = o;
      cursor[idx] = o;
    }
  }
}

// ---- standalone layer GEMM (layers 2,3) -----------------------------------
__global__ __launch_bounds__(256, 2) void k_gemm128(
    const float* __restrict__ A, long long lda,
    const float* __restrict__ W, float* __restrict__ hw, int N) {
  __shared__ __align__(16) float hsT[32][128];
  __shared__ __align__(16) float Ws[32][128];
  gemm128_body(A, lda, W, hw, N, blockIdx.x * 128, hsT, Ws);
}

// ---- segment aggregate:
//   hcat[n] = relu(dinv_n*(dinv_n*hw[n] + sum_in dinv_r*hw[r]) + b)
// one 32-lane group per node, lane owns 4 features; hw is RAW A@W
__global__ __launch_bounds__(256) void k_agg(
    const int* __restrict__ offs, const int* __restrict__ degi,
    const int* __restrict__ sorted_row, const float* __restrict__ dinv,
    const float* __restrict__ hw, const float* __restrict__ bias,
    float* __restrict__ hcat, int koff, int N) {
  const int g = (int)((blockIdx.x * 256 + threadIdx.x) >> 5);
  if (g >= N) return;
  const int j = (threadIdx.x & 31) << 2;
  const float dc = dinv[g];
  const float4 sv = *(const float4*)(hw + (size_t)g * 128 + j);
  float4 acc = make_float4(dc * sv.x, dc * sv.y, dc * sv.z, dc * sv.w);

  const int off = offs[g];
  const int end = off + degi[g];
  int e = off;
  for (; e + 7 < end; e += 8) {  // 8 gathers in flight
    int r[8];
    #pragma unroll
    for (int t = 0; t < 8; ++t) r[t] = sorted_row[e + t];
    float dr[8];
    float4 v[8];
    #pragma unroll
    for (int t = 0; t < 8; ++t) {
      dr[t] = dinv[r[t]];
      v[t] = *(const float4*)(hw + (size_t)r[t] * 128 + j);
    }
    #pragma unroll
    for (int t = 0; t < 8; ++t) {
      acc.x = fmaf(dr[t], v[t].x, acc.x); acc.y = fmaf(dr[t], v[t].y, acc.y);
      acc.z = fmaf(dr[t], v[t].z, acc.z); acc.w = fmaf(dr[t], v[t].w, acc.w);
    }
  }
  for (; e + 3 < end; e += 4) {
    int r[4];
    #pragma unroll
    for (int t = 0; t < 4; ++t) r[t] = sorted_row[e + t];
    float dr[4];
    float4 v[4];
    #pragma unroll
    for (int t = 0; t < 4; ++t) {
      dr[t] = dinv[r[t]];
      v[t] = *(const float4*)(hw + (size_t)r[t] * 128 + j);
    }
    #pragma unroll
    for (int t = 0; t < 4; ++t) {
      acc.x = fmaf(dr[t], v[t].x, acc.x); acc.y = fmaf(dr[t], v[t].y, acc.y);
      acc.z = fmaf(dr[t], v[t].z, acc.z); acc.w = fmaf(dr[t], v[t].w, acc.w);
    }
  }
  for (; e < end; ++e) {
    const int r0 = sorted_row[e];
    const float d0 = dinv[r0];
    const float4 v0 = *(const float4*)(hw + (size_t)r0 * 128 + j);
    acc.x = fmaf(d0, v0.x, acc.x); acc.y = fmaf(d0, v0.y, acc.y);
    acc.z = fmaf(d0, v0.z, acc.z); acc.w = fmaf(d0, v0.w, acc.w);
  }
  const float4 bb = *(const float4*)(bias + j);
  *(float4*)(hcat + (size_t)g * 384 + koff + j) =
      make_float4(fmaxf(fmaf(dc, acc.x, bb.x), 0.f),
                  fmaxf(fmaf(dc, acc.y, bb.y), 0.f),
                  fmaxf(fmaf(dc, acc.z, bb.z), 0.f),
                  fmaxf(fmaf(dc, acc.w, bb.w), 0.f));
}

// ---- final: out = hcat @ Wlin + blin, K=384, 12 chunks of 32 --------------
__global__ __launch_bounds__(256, 2) void k_final(
    const float* __restrict__ hcat, const float* __restrict__ Wlin,
    const float* __restrict__ blin, float* __restrict__ out, int N) {
  __shared__ __align__(16) float hsT[32][128];  // 16KB
  __shared__ __align__(16) float Ws[32][64];    // 8KB
  const int tid = threadIdx.x;
  const int n0 = blockIdx.x * 128;
  const int rows = min(128, N - n0);
  const int tc = (tid & 15) << 2;
  const int tr = (tid >> 4) << 3;
  float acc[8][4] = {};
  float4 pa[4];

  auto loadA = [&](int kc) {
    #pragma unroll
    for (int u = 0; u < 4; ++u) {
      const int i = tid + 256 * u;
      const int r = i >> 3, k4 = (i & 7) << 2;
      float4 v = make_float4(0.f, 0.f, 0.f, 0.f);
      if (r < rows) v = *(const float4*)(hcat + (size_t)(n0 + r) * 384 + kc + k4);
      pa[u] = v;
    }
  };
  auto stageA = [&]() {
    #pragma unroll
    for (int u = 0; u < 4; ++u) {
      const int i = tid + 256 * u;
      const int r = i >> 3, k4 = (i & 7) << 2;
      const int c = r ^ k4;
      hsT[k4 + 0][c] = pa[u].x; hsT[k4 + 1][c] = pa[u].y;
      hsT[k4 + 2][c] = pa[u].z; hsT[k4 + 3][c] = pa[u].w;
    }
  };
  auto stageW = [&](int kc) {
    #pragma unroll
    for (int u = 0; u < 2; ++u) {
      const int i = tid + 256 * u;
      const int k = i >> 4, c = (i & 15) << 2;
      *(float4*)&Ws[k][c] = *(const float4*)(Wlin + (size_t)(kc + k) * 64 + c);
    }
  };

  loadA(0);
  for (int kc = 0; kc < 384; kc += 32) {
    stageW(kc);
    stageA();
    __syncthreads();
    if (kc + 32 < 384) loadA(kc + 32);
    #pragma unroll
    for (int k = 0; k < 32; ++k) {
      const int s = k & 28;
      const float4 a0 = *(const float4*)&hsT[k][tr ^ s];
      const float4 a1 = *(const float4*)&hsT[k][(tr + 4) ^ s];
      const float4 w0 = *(const float4*)&Ws[k][tc];
      const float a[8] = {a0.x, a0.y, a0.z, a0.w, a1.x, a1.y, a1.z, a1.w};
      const float w[4] = {w0.x, w0.y, w0.z, w0.w};
      #pragma unroll
      for (int i = 0; i < 8; ++i)
        #pragma unroll
        for (int j = 0; j < 4; ++j) acc[i][j] = fmaf(a[i], w[j], acc[i][j]);
    }
    __syncthreads();
  }

  #pragma unroll
  for (int i = 0; i < 8; ++i) {
    const int r = tr + i;
    if (r < rows) {
      const float4 bb = *(const float4*)(blin + tc);
      *(float4*)(out + (size_t)(n0 + r) * 64 + tc) =
          make_float4(acc[i][0] + bb.x, acc[i][1] + bb.y,
                      acc[i][2] + bb.z, acc[i][3] + bb.w);
    }
  }
}

extern "C" void kernel_launch(void* const* d_in, const int* in_sizes, int n_in,
                              void* d_out, int out_size, void* d_ws, size_t ws_size,
                              hipStream_t stream) {
  const float* x    = (const float*)d_in[0];
  const int*   ei   = (const int*)d_in[1];
  const float* W1   = (const float*)d_in[2];
  const float* b1   = (const float*)d_in[3];
  const float* W2   = (const float*)d_in[4];
  const float* b2   = (const float*)d_in[5];
  const float* W3   = (const float*)d_in[6];
  const float* b3   = (const float*)d_in[7];
  const float* Wlin = (const float*)d_in[8];
  const float* blin = (const float*)d_in[9];

  const int N = in_sizes[0] / 128;
  const int E = in_sizes[1] / 2;
  const int* rowi = ei;
  const int* coli = ei + E;

  // ws layout: degi | dinv | offs | cursor | bsums | sorted_row | hw | hcat
  char* ws = (char*)d_ws;
  const size_t nb4 = (((size_t)N * 4) + 255) & ~(size_t)255;
  int*   degi       = (int*)ws;                 ws += nb4;
  float* dinv       = (float*)ws;               ws += nb4;
  int*   offs       = (int*)ws;                 ws += nb4;
  int*   cursor     = (int*)ws;                 ws += nb4;
  int*   bsums      = (int*)ws;                 ws += 1024;
  int*   sorted_row = (int*)ws;                 ws += (((size_t)E * 4) + 255) & ~(size_t)255;
  float* hw         = (float*)ws;               ws += (size_t)N * 128 * 4;
  float* hcat       = (float*)ws;

  const int nblk = (N + 1023) / 1024;  // <= 128 for N <= 131072
  const int gemmBlocks = (N + 127) / 128;
  const int gb0 = gemmBlocks / 2;          // gemm1 lower half (mega0)
  const int gb1 = gemmBlocks - gb0;        // gemm1 upper half (mega1)
  const int degBlocks  = (E + 2047) / 2048;
  const int fillBlocks = (E + 1023) / 1024;
  const int aggBlocks  = (N + 7) / 8;

  hipMemsetAsync(degi, 0, (size_t)N * 4, stream);
  k_mega0<<<gb0 + degBlocks, 256, 0, stream>>>(x, W1, hw, N, gb0, coli, E, degi);
  k_scan1<<<nblk, 256, 0, stream>>>(degi, N, offs, bsums, dinv);
  k_scan2<<<1, 128, 0, stream>>>(bsums, nblk);
  k_scan3<<<nblk, 256, 0, stream>>>(offs, bsums, cursor, N);
  k_mega1<<<gb1 + fillBlocks, 256, 0, stream>>>(x, W1, hw, N, gb1, gb0,
                                                rowi, coli, cursor, sorted_row, E);

  k_agg<<<aggBlocks, 256, 0, stream>>>(offs, degi, sorted_row, dinv, hw,
                                       b1, hcat, 0, N);
  k_gemm128<<<gemmBlocks, 256, 0, stream>>>(hcat, 384, W2, hw, N);
  k_agg<<<aggBlocks, 256, 0, stream>>>(offs, degi, sorted_row, dinv, hw,
                                       b2, hcat, 128, N);
  k_gemm128<<<gemmBlocks, 256, 0, stream>>>(hcat + 128, 384, W3, hw, N);
  k_agg<<<aggBlocks, 256, 0, stream>>>(offs, degi, sorted_row, dinv, hw,
                                       b3, hcat, 256, N);
  k_final<<<gemmBlocks, 256, 0, stream>>>(hcat, Wlin, blin, (float*)d_out, N);
}

// Round 8
// 563.048 us; speedup vs baseline: 2.0751x; 1.3094x over previous
//
#include <hip/hip_runtime.h>
#include <hip/hip_bf16.h>

// ---------------------------------------------------------------------------
// GCN via device-built CSR (no f32 atomics):
//   mega0 = [gemm1 lower half | deg count]   (independent -> co-scheduled)
//   scan(+dinv) ; mega1 = [gemm1 upper half | CSR bucket fill]
//   3x [ hw = bf16(hprev @ W) (raw) ;
//        hcat_k[n] = relu(dinv_n*(dinv_n*hw[n] + sum_in dinv_r*hw[r]) + b) ]
//   out = hcat @ Wlin + blin
// hw stored bf16: halves the 819MB/layer random gather in k_agg (the
// dominant cost, L3-fabric-BW bound at ~4TB/s).
// GEMMs: K=32 LDS chunks, A-stream reg prefetch, W direct to LDS,
// __launch_bounds__(256,2) = 128-VGPR cap = spill-free (arg>=3 spills).
// ---------------------------------------------------------------------------

__device__ __forceinline__ unsigned short f2bf(float f) {  // RNE f32->bf16
  unsigned int u = __float_as_uint(f);
  u += 0x7FFFu + ((u >> 16) & 1u);
  return (unsigned short)(u >> 16);
}
__device__ __forceinline__ float bf2f(unsigned short h) {
  return __uint_as_float((unsigned int)h << 16);
}

// ---- shared GEMM-128 body (A [N x lda] @ W [128x128] -> hw bf16 raw) ------
__device__ __forceinline__ void gemm128_body(
    const float* __restrict__ A, long long lda,
    const float* __restrict__ W, unsigned short* __restrict__ hw, int N, int n0,
    float (*hsT)[128], float (*Ws)[128]) {
  const int tid = threadIdx.x;
  const int rows = min(128, N - n0);
  const int tc4 = (tid & 15) << 2;   // col group 1: tc4..+3; group 2: +64
  const int tr = (tid >> 4) << 3;    // 8 rows
  float acc[8][8] = {};
  float4 pa[4];

  auto loadA = [&](int kc) {
    #pragma unroll
    for (int u = 0; u < 4; ++u) {
      const int i = tid + 256 * u;
      const int r = i >> 3, k4 = (i & 7) << 2;
      float4 v = make_float4(0.f, 0.f, 0.f, 0.f);
      if (r < rows) v = *(const float4*)(A + (size_t)(n0 + r) * lda + kc + k4);
      pa[u] = v;
    }
  };
  auto stageA = [&]() {
    #pragma unroll
    for (int u = 0; u < 4; ++u) {
      const int i = tid + 256 * u;
      const int r = i >> 3, k4 = (i & 7) << 2;
      const int c = r ^ k4;  // k4 in {0..28}
      hsT[k4 + 0][c] = pa[u].x; hsT[k4 + 1][c] = pa[u].y;
      hsT[k4 + 2][c] = pa[u].z; hsT[k4 + 3][c] = pa[u].w;
    }
  };
  auto stageW = [&](int kc) {  // direct global->LDS (L2-hot)
    #pragma unroll
    for (int u = 0; u < 4; ++u) {
      const int i = tid + 256 * u;
      const int k = i >> 5, c = (i & 31) << 2;
      *(float4*)&Ws[k][c] = *(const float4*)(W + (size_t)(kc + k) * 128 + c);
    }
  };

  loadA(0);
  for (int kc = 0; kc < 128; kc += 32) {
    stageW(kc);
    stageA();
    __syncthreads();
    if (kc + 32 < 128) loadA(kc + 32);  // prefetch next A chunk into regs
    #pragma unroll
    for (int k = 0; k < 32; ++k) {
      const int s = k & 28;
      const float4 a0 = *(const float4*)&hsT[k][tr ^ s];
      const float4 a1 = *(const float4*)&hsT[k][(tr + 4) ^ s];
      const float4 w0 = *(const float4*)&Ws[k][tc4];        // 256B/wave
      const float4 w1 = *(const float4*)&Ws[k][tc4 + 64];   // 256B/wave
      const float a[8] = {a0.x, a0.y, a0.z, a0.w, a1.x, a1.y, a1.z, a1.w};
      const float w[8] = {w0.x, w0.y, w0.z, w0.w, w1.x, w1.y, w1.z, w1.w};
      #pragma unroll
      for (int i = 0; i < 8; ++i)
        #pragma unroll
        for (int j = 0; j < 8; ++j) acc[i][j] = fmaf(a[i], w[j], acc[i][j]);
    }
    __syncthreads();
  }

  #pragma unroll
  for (int i = 0; i < 8; ++i) {
    const int r = tr + i;
    if (r < rows) {
      unsigned short* hwp = hw + (size_t)(n0 + r) * 128;
      ushort4 o0, o1;
      o0.x = f2bf(acc[i][0]); o0.y = f2bf(acc[i][1]);
      o0.z = f2bf(acc[i][2]); o0.w = f2bf(acc[i][3]);
      o1.x = f2bf(acc[i][4]); o1.y = f2bf(acc[i][5]);
      o1.z = f2bf(acc[i][6]); o1.w = f2bf(acc[i][7]);
      *(ushort4*)(hwp + tc4) = o0;
      *(ushort4*)(hwp + tc4 + 64) = o1;
    }
  }
}

// ---- mega0: [gemm1 lower | degree count] ----------------------------------
__global__ __launch_bounds__(256, 2) void k_mega0(
    const float* __restrict__ x, const float* __restrict__ W1,
    unsigned short* __restrict__ hw, int N, int gb,
    const int* __restrict__ coli, int E, int* __restrict__ degi) {
  __shared__ __align__(16) float hsT[32][128];
  __shared__ __align__(16) float Ws[32][128];
  if ((int)blockIdx.x < gb) {
    gemm128_body(x, 128, W1, hw, N, blockIdx.x * 128, hsT, Ws);
  } else {
    const int b = blockIdx.x - gb;
    #pragma unroll
    for (int h = 0; h < 2; ++h) {
      const int base = b * 2048 + h * 1024 + (int)threadIdx.x * 4;
      if (base + 3 < E) {
        const int4 c4 = *(const int4*)(coli + base);
        atomicAdd(&degi[c4.x], 1); atomicAdd(&degi[c4.y], 1);
        atomicAdd(&degi[c4.z], 1); atomicAdd(&degi[c4.w], 1);
      } else {
        for (int e = base; e < E; ++e) atomicAdd(&degi[coli[e]], 1);
      }
    }
  }
}

// ---- mega1: [gemm1 upper | CSR bucket fill] -------------------------------
__global__ __launch_bounds__(256, 2) void k_mega1(
    const float* __restrict__ x, const float* __restrict__ W1,
    unsigned short* __restrict__ hw, int N, int gb, int goff,
    const int* __restrict__ rowi, const int* __restrict__ coli,
    int* __restrict__ cursor, int* __restrict__ sorted_row, int E) {
  __shared__ __align__(16) float hsT[32][128];
  __shared__ __align__(16) float Ws[32][128];
  if ((int)blockIdx.x < gb) {
    gemm128_body(x, 128, W1, hw, N, (goff + blockIdx.x) * 128, hsT, Ws);
  } else {
    const int b = blockIdx.x - gb;
    const int base = b * 1024 + (int)threadIdx.x * 4;
    if (base + 3 < E) {
      const int4 c4 = *(const int4*)(coli + base);
      const int4 r4 = *(const int4*)(rowi + base);
      int p;
      p = atomicAdd(&cursor[c4.x], 1); sorted_row[p] = r4.x;
      p = atomicAdd(&cursor[c4.y], 1); sorted_row[p] = r4.y;
      p = atomicAdd(&cursor[c4.z], 1); sorted_row[p] = r4.z;
      p = atomicAdd(&cursor[c4.w], 1); sorted_row[p] = r4.w;
    } else {
      for (int e = base; e < E; ++e) {
        const int p = atomicAdd(&cursor[coli[e]], 1);
        sorted_row[p] = rowi[e];
      }
    }
  }
}

// ---- scan pass 1: per-1024-chunk exclusive scan + block sums + dinv -------
__global__ __launch_bounds__(256) void k_scan1(const int* __restrict__ degi, int N,
                                               int* __restrict__ offs,
                                               int* __restrict__ bsums,
                                               float* __restrict__ dinv) {
  __shared__ int sm[256];
  const int b = blockIdx.x, t = threadIdx.x;
  const int base = b * 1024 + t * 4;
  int v[4];
  #pragma unroll
  for (int i = 0; i < 4; ++i) v[i] = (base + i < N) ? degi[base + i] : 0;
  #pragma unroll
  for (int i = 0; i < 4; ++i)
    if (base + i < N) dinv[base + i] = rsqrtf(1.0f + (float)v[i]);
  const int s = v[0] + v[1] + v[2] + v[3];
  sm[t] = s;
  __syncthreads();
  for (int ofs = 1; ofs < 256; ofs <<= 1) {
    const int add = (t >= ofs) ? sm[t - ofs] : 0;
    __syncthreads();
    sm[t] += add;
    __syncthreads();
  }
  if (t == 255) bsums[b] = sm[255];
  int run = sm[t] - s;
  #pragma unroll
  for (int i = 0; i < 4; ++i) {
    if (base + i < N) offs[base + i] = run;
    run += v[i];
  }
}

// ---- scan pass 2: exclusive scan of block sums (nb <= 128) ----------------
__global__ __launch_bounds__(128) void k_scan2(int* __restrict__ bsums, int nb) {
  __shared__ int sm[128];
  const int t = threadIdx.x;
  const int v = (t < nb) ? bsums[t] : 0;
  sm[t] = v;
  __syncthreads();
  for (int ofs = 1; ofs < 128; ofs <<= 1) {
    const int add = (t >= ofs) ? sm[t - ofs] : 0;
    __syncthreads();
    sm[t] += add;
    __syncthreads();
  }
  if (t < nb) bsums[t] = sm[t] - v;
}

// ---- scan pass 3: add block offset; copy to cursor ------------------------
__global__ __launch_bounds__(256) void k_scan3(int* __restrict__ offs,
                                               const int* __restrict__ bsums,
                                               int* __restrict__ cursor, int N) {
  const int add = bsums[blockIdx.x];
  const int base = blockIdx.x * 1024 + threadIdx.x * 4;
  #pragma unroll
  for (int i = 0; i < 4; ++i) {
    const int idx = base + i;
    if (idx < N) {
      const int o = offs[idx] + add;
      offs[idx] = o;
      cursor[idx] = o;
    }
  }
}

// ---- standalone layer GEMM (layers 2,3) -----------------------------------
__global__ __launch_bounds__(256, 2) void k_gemm128(
    const float* __restrict__ A, long long lda,
    const float* __restrict__ W, unsigned short* __restrict__ hw, int N) {
  __shared__ __align__(16) float hsT[32][128];
  __shared__ __align__(16) float Ws[32][128];
  gemm128_body(A, lda, W, hw, N, blockIdx.x * 128, hsT, Ws);
}

// ---- segment aggregate:
//   hcat[n] = relu(dinv_n*(dinv_n*hw[n] + sum_in dinv_r*hw[r]) + b)
// one 32-lane group per node, lane owns 4 features; hw is bf16 RAW A@W
__global__ __launch_bounds__(256) void k_agg(
    const int* __restrict__ offs, const int* __restrict__ degi,
    const int* __restrict__ sorted_row, const float* __restrict__ dinv,
    const unsigned short* __restrict__ hw, const float* __restrict__ bias,
    float* __restrict__ hcat, int koff, int N) {
  const int g = (int)((blockIdx.x * 256 + threadIdx.x) >> 5);
  if (g >= N) return;
  const int j = (threadIdx.x & 31) << 2;
  const float dc = dinv[g];
  const ushort4 sv = *(const ushort4*)(hw + (size_t)g * 128 + j);
  float4 acc = make_float4(dc * bf2f(sv.x), dc * bf2f(sv.y),
                           dc * bf2f(sv.z), dc * bf2f(sv.w));

  const int off = offs[g];
  const int end = off + degi[g];
  int e = off;
  for (; e + 7 < end; e += 8) {  // 8 gathers in flight
    int r[8];
    #pragma unroll
    for (int t = 0; t < 8; ++t) r[t] = sorted_row[e + t];
    float dr[8];
    ushort4 v[8];
    #pragma unroll
    for (int t = 0; t < 8; ++t) {
      dr[t] = dinv[r[t]];
      v[t] = *(const ushort4*)(hw + (size_t)r[t] * 128 + j);
    }
    #pragma unroll
    for (int t = 0; t < 8; ++t) {
      acc.x = fmaf(dr[t], bf2f(v[t].x), acc.x);
      acc.y = fmaf(dr[t], bf2f(v[t].y), acc.y);
      acc.z = fmaf(dr[t], bf2f(v[t].z), acc.z);
      acc.w = fmaf(dr[t], bf2f(v[t].w), acc.w);
    }
  }
  for (; e + 3 < end; e += 4) {
    int r[4];
    #pragma unroll
    for (int t = 0; t < 4; ++t) r[t] = sorted_row[e + t];
    float dr[4];
    ushort4 v[4];
    #pragma unroll
    for (int t = 0; t < 4; ++t) {
      dr[t] = dinv[r[t]];
      v[t] = *(const ushort4*)(hw + (size_t)r[t] * 128 + j);
    }
    #pragma unroll
    for (int t = 0; t < 4; ++t) {
      acc.x = fmaf(dr[t], bf2f(v[t].x), acc.x);
      acc.y = fmaf(dr[t], bf2f(v[t].y), acc.y);
      acc.z = fmaf(dr[t], bf2f(v[t].z), acc.z);
      acc.w = fmaf(dr[t], bf2f(v[t].w), acc.w);
    }
  }
  for (; e < end; ++e) {
    const int r0 = sorted_row[e];
    const float d0 = dinv[r0];
    const ushort4 v0 = *(const ushort4*)(hw + (size_t)r0 * 128 + j);
    acc.x = fmaf(d0, bf2f(v0.x), acc.x);
    acc.y = fmaf(d0, bf2f(v0.y), acc.y);
    acc.z = fmaf(d0, bf2f(v0.z), acc.z);
    acc.w = fmaf(d0, bf2f(v0.w), acc.w);
  }
  const float4 bb = *(const float4*)(bias + j);
  *(float4*)(hcat + (size_t)g * 384 + koff + j) =
      make_float4(fmaxf(fmaf(dc, acc.x, bb.x), 0.f),
                  fmaxf(fmaf(dc, acc.y, bb.y), 0.f),
                  fmaxf(fmaf(dc, acc.z, bb.z), 0.f),
                  fmaxf(fmaf(dc, acc.w, bb.w), 0.f));
}

// ---- final: out = hcat @ Wlin + blin, K=384, 12 chunks of 32 --------------
__global__ __launch_bounds__(256, 2) void k_final(
    const float* __restrict__ hcat, const float* __restrict__ Wlin,
    const float* __restrict__ blin, float* __restrict__ out, int N) {
  __shared__ __align__(16) float hsT[32][128];  // 16KB
  __shared__ __align__(16) float Ws[32][64];    // 8KB
  const int tid = threadIdx.x;
  const int n0 = blockIdx.x * 128;
  const int rows = min(128, N - n0);
  const int tc = (tid & 15) << 2;
  const int tr = (tid >> 4) << 3;
  float acc[8][4] = {};
  float4 pa[4];

  auto loadA = [&](int kc) {
    #pragma unroll
    for (int u = 0; u < 4; ++u) {
      const int i = tid + 256 * u;
      const int r = i >> 3, k4 = (i & 7) << 2;
      float4 v = make_float4(0.f, 0.f, 0.f, 0.f);
      if (r < rows) v = *(const float4*)(hcat + (size_t)(n0 + r) * 384 + kc + k4);
      pa[u] = v;
    }
  };
  auto stageA = [&]() {
    #pragma unroll
    for (int u = 0; u < 4; ++u) {
      const int i = tid + 256 * u;
      const int r = i >> 3, k4 = (i & 7) << 2;
      const int c = r ^ k4;
      hsT[k4 + 0][c] = pa[u].x; hsT[k4 + 1][c] = pa[u].y;
      hsT[k4 + 2][c] = pa[u].z; hsT[k4 + 3][c] = pa[u].w;
    }
  };
  auto stageW = [&](int kc) {
    #pragma unroll
    for (int u = 0; u < 2; ++u) {
      const int i = tid + 256 * u;
      const int k = i >> 4, c = (i & 15) << 2;
      *(float4*)&Ws[k][c] = *(const float4*)(Wlin + (size_t)(kc + k) * 64 + c);
    }
  };

  loadA(0);
  for (int kc = 0; kc < 384; kc += 32) {
    stageW(kc);
    stageA();
    __syncthreads();
    if (kc + 32 < 384) loadA(kc + 32);
    #pragma unroll
    for (int k = 0; k < 32; ++k) {
      const int s = k & 28;
      const float4 a0 = *(const float4*)&hsT[k][tr ^ s];
      const float4 a1 = *(const float4*)&hsT[k][(tr + 4) ^ s];
      const float4 w0 = *(const float4*)&Ws[k][tc];
      const float a[8] = {a0.x, a0.y, a0.z, a0.w, a1.x, a1.y, a1.z, a1.w};
      const float w[4] = {w0.x, w0.y, w0.z, w0.w};
      #pragma unroll
      for (int i = 0; i < 8; ++i)
        #pragma unroll
        for (int j = 0; j < 4; ++j) acc[i][j] = fmaf(a[i], w[j], acc[i][j]);
    }
    __syncthreads();
  }

  #pragma unroll
  for (int i = 0; i < 8; ++i) {
    const int r = tr + i;
    if (r < rows) {
      const float4 bb = *(const float4*)(blin + tc);
      *(float4*)(out + (size_t)(n0 + r) * 64 + tc) =
          make_float4(acc[i][0] + bb.x, acc[i][1] + bb.y,
                      acc[i][2] + bb.z, acc[i][3] + bb.w);
    }
  }
}

extern "C" void kernel_launch(void* const* d_in, const int* in_sizes, int n_in,
                              void* d_out, int out_size, void* d_ws, size_t ws_size,
                              hipStream_t stream) {
  const float* x    = (const float*)d_in[0];
  const int*   ei   = (const int*)d_in[1];
  const float* W1   = (const float*)d_in[2];
  const float* b1   = (const float*)d_in[3];
  const float* W2   = (const float*)d_in[4];
  const float* b2   = (const float*)d_in[5];
  const float* W3   = (const float*)d_in[6];
  const float* b3   = (const float*)d_in[7];
  const float* Wlin = (const float*)d_in[8];
  const float* blin = (const float*)d_in[9];

  const int N = in_sizes[0] / 128;
  const int E = in_sizes[1] / 2;
  const int* rowi = ei;
  const int* coli = ei + E;

  // ws layout: degi | dinv | offs | cursor | bsums | sorted_row | hw(bf16) | hcat
  char* ws = (char*)d_ws;
  const size_t nb4 = (((size_t)N * 4) + 255) & ~(size_t)255;
  int*   degi       = (int*)ws;                 ws += nb4;
  float* dinv       = (float*)ws;               ws += nb4;
  int*   offs       = (int*)ws;                 ws += nb4;
  int*   cursor     = (int*)ws;                 ws += nb4;
  int*   bsums      = (int*)ws;                 ws += 1024;
  int*   sorted_row = (int*)ws;                 ws += (((size_t)E * 4) + 255) & ~(size_t)255;
  unsigned short* hw = (unsigned short*)ws;     ws += (size_t)N * 128 * 2;
  float* hcat       = (float*)ws;

  const int nblk = (N + 1023) / 1024;  // <= 128 for N <= 131072
  const int gemmBlocks = (N + 127) / 128;
  const int gb0 = gemmBlocks / 2;          // gemm1 lower half (mega0)
  const int gb1 = gemmBlocks - gb0;        // gemm1 upper half (mega1)
  const int degBlocks  = (E + 2047) / 2048;
  const int fillBlocks = (E + 1023) / 1024;
  const int aggBlocks  = (N + 7) / 8;

  hipMemsetAsync(degi, 0, (size_t)N * 4, stream);
  k_mega0<<<gb0 + degBlocks, 256, 0, stream>>>(x, W1, hw, N, gb0, coli, E, degi);
  k_scan1<<<nblk, 256, 0, stream>>>(degi, N, offs, bsums, dinv);
  k_scan2<<<1, 128, 0, stream>>>(bsums, nblk);
  k_scan3<<<nblk, 256, 0, stream>>>(offs, bsums, cursor, N);
  k_mega1<<<gb1 + fillBlocks, 256, 0, stream>>>(x, W1, hw, N, gb1, gb0,
                                                rowi, coli, cursor, sorted_row, E);

  k_agg<<<aggBlocks, 256, 0, stream>>>(offs, degi, sorted_row, dinv, hw,
                                       b1, hcat, 0, N);
  k_gemm128<<<gemmBlocks, 256, 0, stream>>>(hcat, 384, W2, hw, N);
  k_agg<<<aggBlocks, 256, 0, stream>>>(offs, degi, sorted_row, dinv, hw,
                                       b2, hcat, 128, N);
  k_gemm128<<<gemmBlocks, 256, 0, stream>>>(hcat + 128, 384, W3, hw, N);
  k_agg<<<aggBlocks, 256, 0, stream>>>(offs, degi, sorted_row, dinv, hw,
                                       b3, hcat, 256, N);
  k_final<<<gemmBlocks, 256, 0, stream>>>(hcat, Wlin, blin, (float*)d_out, N);
}